// Round 5
// baseline (297.533 us; speedup 1.0000x reference)
//
#include <hip/hip_runtime.h>

#define Bn 4
#define Nn 4096000
#define Kn 409664
#define R0c 3686399u   // rank of v_lo; mask == key > key_lo exactly (adjacent order stats)
#define NWC 4000       // 1024-element wave-chunks per sample
#define CAP 4096       // candidate buffer capacity per sample (expect ~250)

// ws offsets (u32 units)
#define H1_OFF 0                     // Bn*2048
#define H2_OFF (H1_OFF + Bn*2048)    // Bn*2048
#define H3_OFF (H2_OFF + Bn*2048)    // Bn*1024
#define ST_OFF (H3_OFF + Bn*1024)    // Bn*2  {prefix/key, rem}
#define CNT_OFF (ST_OFF + Bn*2)      // Bn    per-sample totals
#define CN_OFF (CNT_OFF + Bn)        // Bn    candidate counters
#define BC_OFF (CN_OFF + Bn)         // Bn*NWC wave-chunk counts -> exclusive prefix
#define CAND_OFF (BC_OFF + Bn*NWC)   // Bn*CAP packed (wc<<10)|low10

#define OUT_SP  ((size_t)Bn * Kn * 5)
#define OUT_VAL ((size_t)Bn * Kn * 9)

__device__ __forceinline__ unsigned fkey(float x) {
    unsigned u = __float_as_uint(x);
    return u ^ ((unsigned)((int)u >> 31) | 0x80000000u);
}

// ---------------- hist1: top 11 bits, 2 LDS copies, grid Bn*1000 ----------------
__global__ __launch_bounds__(256) void hist1_k(const float* __restrict__ cube,
                                               unsigned* __restrict__ ws) {
    __shared__ unsigned h[2][2048];
    int tid = threadIdx.x, blk = blockIdx.x;
    int b = blk / 1000, c = blk % 1000;
    for (int j = tid; j < 4096; j += 256) ((unsigned*)h)[j] = 0;
    __syncthreads();
    const float4* p = (const float4*)(cube + (size_t)b * Nn + (size_t)c * 4096);
    float4 v0 = p[tid], v1 = p[256 + tid], v2 = p[512 + tid], v3 = p[768 + tid];
    unsigned* hh = h[tid >> 7];
    atomicAdd(&hh[fkey(v0.x) >> 21], 1u); atomicAdd(&hh[fkey(v0.y) >> 21], 1u);
    atomicAdd(&hh[fkey(v0.z) >> 21], 1u); atomicAdd(&hh[fkey(v0.w) >> 21], 1u);
    atomicAdd(&hh[fkey(v1.x) >> 21], 1u); atomicAdd(&hh[fkey(v1.y) >> 21], 1u);
    atomicAdd(&hh[fkey(v1.z) >> 21], 1u); atomicAdd(&hh[fkey(v1.w) >> 21], 1u);
    atomicAdd(&hh[fkey(v2.x) >> 21], 1u); atomicAdd(&hh[fkey(v2.y) >> 21], 1u);
    atomicAdd(&hh[fkey(v2.z) >> 21], 1u); atomicAdd(&hh[fkey(v2.w) >> 21], 1u);
    atomicAdd(&hh[fkey(v3.x) >> 21], 1u); atomicAdd(&hh[fkey(v3.y) >> 21], 1u);
    atomicAdd(&hh[fkey(v3.z) >> 21], 1u); atomicAdd(&hh[fkey(v3.w) >> 21], 1u);
    __syncthreads();
    unsigned* g = ws + H1_OFF + b * 2048;
    for (int j = tid; j < 2048; j += 256) {
        unsigned s = h[0][j] + h[1][j];
        if (s) atomicAdd(&g[j], s);
    }
}

// ---------------- pick1 (also zeroes candidate counters) ----------------
__global__ __launch_bounds__(256) void pick1_k(unsigned* __restrict__ ws) {
    __shared__ unsigned sh[256];
    int tid = threadIdx.x, b = blockIdx.x;
    if (tid == 0) ws[CN_OFF + b] = 0;
    const unsigned* hist = ws + H1_OFF + b * 2048;
    unsigned loc[8], lsum = 0;
    for (int j = 0; j < 8; ++j) { loc[j] = hist[tid * 8 + j]; lsum += loc[j]; }
    sh[tid] = lsum; __syncthreads();
    for (int off = 1; off < 256; off <<= 1) {
        unsigned v = (tid >= off) ? sh[tid - off] : 0u; __syncthreads();
        sh[tid] += v; __syncthreads();
    }
    unsigned base = tid ? sh[tid - 1] : 0u;
    if (R0c >= base && R0c < base + lsum) {
        unsigned cacc = base;
        for (int j = 0; j < 8; ++j) {
            if (R0c < cacc + loc[j]) {
                ws[ST_OFF + b * 2] = (unsigned)(tid * 8 + j);
                ws[ST_OFF + b * 2 + 1] = R0c - cacc;
                break;
            }
            cacc += loc[j];
        }
    }
}

// ---------------- hist2: middle 11 bits gated on 11-bit prefix ----------------
__global__ __launch_bounds__(256) void hist2_k(const float* __restrict__ cube,
                                               unsigned* __restrict__ ws) {
    __shared__ unsigned h[2048];
    int tid = threadIdx.x, blk = blockIdx.x;
    int b = blk / 1000, c = blk % 1000;
    unsigned p11 = ws[ST_OFF + b * 2];
    for (int j = tid; j < 2048; j += 256) h[j] = 0;
    __syncthreads();
    const float4* p = (const float4*)(cube + (size_t)b * Nn + (size_t)c * 4096);
    float4 v0 = p[tid], v1 = p[256 + tid], v2 = p[512 + tid], v3 = p[768 + tid];
    float vv[16] = {v0.x, v0.y, v0.z, v0.w, v1.x, v1.y, v1.z, v1.w,
                    v2.x, v2.y, v2.z, v2.w, v3.x, v3.y, v3.z, v3.w};
#pragma unroll
    for (int q = 0; q < 16; ++q) {
        unsigned k = fkey(vv[q]);
        if ((k >> 21) == p11) atomicAdd(&h[(k >> 10) & 0x7FFu], 1u);
    }
    __syncthreads();
    unsigned* g = ws + H2_OFF + b * 2048;
    for (int j = tid; j < 2048; j += 256) if (h[j]) atomicAdd(&g[j], h[j]);
}

__global__ __launch_bounds__(256) void pick2_k(unsigned* __restrict__ ws) {
    __shared__ unsigned sh[256];
    int tid = threadIdx.x, b = blockIdx.x;
    const unsigned* hist = ws + H2_OFF + b * 2048;
    unsigned r = ws[ST_OFF + b * 2 + 1];
    unsigned pref = ws[ST_OFF + b * 2];
    unsigned loc[8], lsum = 0;
    for (int j = 0; j < 8; ++j) { loc[j] = hist[tid * 8 + j]; lsum += loc[j]; }
    sh[tid] = lsum; __syncthreads();
    for (int off = 1; off < 256; off <<= 1) {
        unsigned v = (tid >= off) ? sh[tid - off] : 0u; __syncthreads();
        sh[tid] += v; __syncthreads();
    }
    unsigned base = tid ? sh[tid - 1] : 0u;
    if (r >= base && r < base + lsum) {
        unsigned cacc = base;
        for (int j = 0; j < 8; ++j) {
            if (r < cacc + loc[j]) {
                ws[ST_OFF + b * 2] = (pref << 11) | (unsigned)(tid * 8 + j);
                ws[ST_OFF + b * 2 + 1] = r - cacc;
                break;
            }
            cacc += loc[j];
        }
    }
}

// ---------------- pass5: per-chunk A-counts + candidate compact + hist3 ----------------
// one 1024-element chunk per wave; order within chunk irrelevant here
__global__ __launch_bounds__(256) void pass5_k(const float* __restrict__ cube,
                                               unsigned* __restrict__ ws) {
    int tid = threadIdx.x, blk = blockIdx.x;
    int lane = tid & 63, wid = tid >> 6;
    int b = blk / 1000, c = blk % 1000;
    unsigned p22 = ws[ST_OFF + b * 2];
    unsigned* H3g = ws + H3_OFF + b * 1024;
    int wc = c * 4 + wid;
    const float4* p = (const float4*)(cube + (size_t)b * Nn + (size_t)wc * 1024);
    float4 v0 = p[lane], v1 = p[64 + lane], v2 = p[128 + lane], v3 = p[192 + lane];
    float vv[16] = {v0.x, v0.y, v0.z, v0.w, v1.x, v1.y, v1.z, v1.w,
                    v2.x, v2.y, v2.z, v2.w, v3.x, v3.y, v3.z, v3.w};
    unsigned acnt = 0;
#pragma unroll
    for (int q = 0; q < 16; ++q) {
        unsigned k = fkey(vv[q]);
        acnt += ((k >> 10) > p22) ? 1u : 0u;
        if ((k >> 10) == p22) {
            unsigned t = atomicAdd(&ws[CN_OFF + b], 1u);
            if (t < CAP) ws[CAND_OFF + b * CAP + t] = ((unsigned)wc << 10) | (k & 1023u);
            atomicAdd(&H3g[k & 1023u], 1u);
        }
    }
    for (int off = 32; off > 0; off >>= 1) acnt += __shfl_down(acnt, off, 64);
    if (lane == 0) ws[BC_OFF + b * NWC + wc] = acnt;
}

// ---------------- finalize: pick3 + candidate fixup + 4000-entry scan ----------------
__global__ __launch_bounds__(256) void finalize_k(unsigned* __restrict__ ws) {
    __shared__ unsigned sh[256];
    __shared__ unsigned bcs[NWC];
    __shared__ unsigned keysh;
    int tid = threadIdx.x, b = blockIdx.x;

    {
        const unsigned* hist = ws + H3_OFF + b * 1024;
        unsigned r = ws[ST_OFF + b * 2 + 1];
        unsigned pref = ws[ST_OFF + b * 2];
        unsigned loc[4], lsum = 0;
        for (int j = 0; j < 4; ++j) { loc[j] = hist[tid * 4 + j]; lsum += loc[j]; }
        sh[tid] = lsum; __syncthreads();
        for (int off = 1; off < 256; off <<= 1) {
            unsigned v = (tid >= off) ? sh[tid - off] : 0u; __syncthreads();
            sh[tid] += v; __syncthreads();
        }
        unsigned base = tid ? sh[tid - 1] : 0u;
        if (r >= base && r < base + lsum) {
            unsigned cacc = base;
            for (int j = 0; j < 4; ++j) {
                if (r < cacc + loc[j]) {
                    unsigned key = (pref << 10) | (unsigned)(tid * 4 + j);
                    keysh = key;
                    ws[ST_OFF + b * 2] = key;   // scatter reads this
                    break;
                }
                cacc += loc[j];
            }
        }
    }
    __syncthreads();
    unsigned lo10 = keysh & 1023u;

    unsigned* bc = ws + BC_OFF + b * NWC;
    for (int j = tid; j < NWC; j += 256) bcs[j] = bc[j];
    unsigned n = ws[CN_OFF + b]; if (n > CAP) n = CAP;
    __syncthreads();
    for (unsigned t = tid; t < n; t += 256) {
        unsigned e = ws[CAND_OFF + b * CAP + t];
        if ((e & 1023u) > lo10) atomicAdd(&bcs[e >> 10], 1u);
    }
    __syncthreads();

    unsigned loc[16], lsum = 0;
    for (int j = 0; j < 16; ++j) {
        int idx = tid * 16 + j;
        loc[j] = (idx < NWC) ? bcs[idx] : 0u;
        lsum += loc[j];
    }
    sh[tid] = lsum; __syncthreads();
    for (int off = 1; off < 256; off <<= 1) {
        unsigned v = (tid >= off) ? sh[tid - off] : 0u; __syncthreads();
        sh[tid] += v; __syncthreads();
    }
    unsigned run = tid ? sh[tid - 1] : 0u;
    for (int j = 0; j < 16; ++j) {
        int idx = tid * 16 + j;
        if (idx < NWC) bc[idx] = run;
        run += loc[j];
    }
    if (tid == 255) ws[CNT_OFF + b] = sh[255];
}

// ---------------- scatter: one chunk per wave, loads decoupled from rank chain ----------------
__global__ __launch_bounds__(256) void scatter_k(const float* __restrict__ cube,
                                                 const float* __restrict__ dop,
                                                 float* __restrict__ out,
                                                 const unsigned* __restrict__ ws) {
    int tid = threadIdx.x, blk = blockIdx.x;
    int lane = tid & 63, wid = tid >> 6;
    int b = blk / 1000, c = blk % 1000;
    const float* cb = cube + (size_t)b * Nn;
    const float* db = dop + (size_t)b * Nn;
    unsigned keylo = ws[ST_OFF + b * 2];
    int wc = c * 4 + wid;
    unsigned run = ws[BC_OFF + b * NWC + wc];
    int base = wc * 1024;

    // decouple: issue all 16 loads before the serial ballot/rank chain
    float xv[16];
#pragma unroll
    for (int it = 0; it < 16; ++it) xv[it] = cb[base + it * 64 + lane];

#pragma unroll
    for (int it = 0; it < 16; ++it) {
        int i = base + it * 64 + lane;
        float x = xv[it];
        bool m = fkey(x) > keylo;
        unsigned long long bal = __ballot(m);
        if (m) {
            unsigned k = run + (unsigned)__popcll(bal & ((1ull << lane) - 1ull));
            size_t row = (size_t)b * Kn + k;
            int xi = i % 320;
            int t2 = i / 320;
            int yi = t2 % 320;
            int zi = t2 / 320;
            float* f = out + row * 5;
            f[0] = (float)xi / 320.0f * 72.0f;
            f[1] = (float)yi / 320.0f * 32.0f;
            f[2] = (float)zi / 40.0f * 8.0f;
            f[3] = x / 1e13f;
            f[4] = db[i] - 1.9326f;
            float4* s4 = (float4*)(out + OUT_SP + row * 4);
            *s4 = make_float4((float)b, (float)zi, (float)yi, (float)xi);
            out[OUT_VAL + row] = 1.0f;
        }
        run += (unsigned)__popcll(bal);
    }
    // tail fill (outputs re-poisoned before every launch)
    for (int g = blk * 256 + tid; g < Bn * Kn; g += 4000 * 256) {
        int bb = g / Kn;
        int k = g - bb * Kn;
        if ((unsigned)k >= ws[CNT_OFF + bb]) {
            size_t row = (size_t)g;
            float* f = out + row * 5;
            f[0] = 0.f; f[1] = 0.f; f[2] = 0.f; f[3] = 0.f; f[4] = 0.f;
            float4* s4 = (float4*)(out + OUT_SP + row * 4);
            *s4 = make_float4(0.f, 0.f, 0.f, 0.f);
            out[OUT_VAL + row] = 0.f;
        }
    }
}

extern "C" void kernel_launch(void* const* d_in, const int* in_sizes, int n_in,
                              void* d_out, int out_size, void* d_ws, size_t ws_size,
                              hipStream_t stream) {
    const float* cube = (const float*)d_in[0];
    const float* dop = (const float*)d_in[1];
    float* out = (float*)d_out;
    unsigned* ws = (unsigned*)d_ws;

    // zero H1/H2/H3 histogram regions only
    hipMemsetAsync(d_ws, 0, (size_t)ST_OFF * sizeof(unsigned), stream);

    hipLaunchKernelGGL(hist1_k,    dim3(Bn * 1000), dim3(256), 0, stream, cube, ws);
    hipLaunchKernelGGL(pick1_k,    dim3(Bn),        dim3(256), 0, stream, ws);
    hipLaunchKernelGGL(hist2_k,    dim3(Bn * 1000), dim3(256), 0, stream, cube, ws);
    hipLaunchKernelGGL(pick2_k,    dim3(Bn),        dim3(256), 0, stream, ws);
    hipLaunchKernelGGL(pass5_k,    dim3(Bn * 1000), dim3(256), 0, stream, cube, ws);
    hipLaunchKernelGGL(finalize_k, dim3(Bn),        dim3(256), 0, stream, ws);
    hipLaunchKernelGGL(scatter_k,  dim3(Bn * 1000), dim3(256), 0, stream, cube, dop, out, ws);
}